// Round 1
// baseline (37.771 us; speedup 1.0000x reference)
//
#include <hip/hip_runtime.h>
#include <stdint.h>

#define KBOX 1024
#define EPSF 1e-4f

// ws layout (bytes):
//   0      : int flag  (1 = bool byte layout, 0 = int32 layout)
//   16     : back [K][12] f32   (48 KB)   rows of inverse affine (3x4)
//   49168  : hp   [K][24] f32   (96 KB)   posed corners xyz
//   147472 : bm   [K][16] u64   (128 KB)  inside bitmask per row
//   278544 : rowCount [K] u32   (4 KB)
//   282640 : rowStart [K] u32   (4 KB)
#define BACK_OFF 16
#define HP_OFF   49168
#define BM_OFF   147472
#define RC_OFF   278544
#define RS_OFF   282640

__global__ void k_flag(const uint8_t* __restrict__ dis, int* flag) {
    __shared__ int s;
    if (threadIdx.x == 0) s = 0;
    __syncthreads();
    int acc = 0;
    for (int i = threadIdx.x; i < 4096; i += 256) {
        if ((i & 3) != 0 && dis[i] != 0) acc = 1;
    }
    if (acc) atomicOr(&s, 1);
    __syncthreads();
    if (threadIdx.x == 0) *flag = s;
}

__global__ void k_pose(const float* __restrict__ bbmin, const float* __restrict__ bbmax,
                       const float* __restrict__ A,
                       float* __restrict__ back, float* __restrict__ hp,
                       float* __restrict__ out_hposed) {
    int k = blockIdx.x * blockDim.x + threadIdx.x;
    if (k >= KBOX) return;
    const float* a = A + (size_t)k * 16;
    float r[3][4];
#pragma unroll
    for (int i = 0; i < 3; ++i)
#pragma unroll
        for (int j = 0; j < 4; ++j) r[i][j] = a[i * 4 + j];

    // double-precision analytic inverse of the 3x3 block
    double m00 = r[0][0], m01 = r[0][1], m02 = r[0][2];
    double m10 = r[1][0], m11 = r[1][1], m12 = r[1][2];
    double m20 = r[2][0], m21 = r[2][1], m22 = r[2][2];
    double c00 = m11 * m22 - m12 * m21;
    double c01 = m12 * m20 - m10 * m22;
    double c02 = m10 * m21 - m11 * m20;
    double det = m00 * c00 + m01 * c01 + m02 * c02;
    double id = 1.0 / det;
    double inv[3][3];
    inv[0][0] = c00 * id;
    inv[0][1] = (m02 * m21 - m01 * m22) * id;
    inv[0][2] = (m01 * m12 - m02 * m11) * id;
    inv[1][0] = c01 * id;
    inv[1][1] = (m00 * m22 - m02 * m20) * id;
    inv[1][2] = (m02 * m10 - m00 * m12) * id;
    inv[2][0] = c02 * id;
    inv[2][1] = (m01 * m20 - m00 * m21) * id;
    inv[2][2] = (m00 * m11 - m01 * m10) * id;
    double tx = r[0][3], ty = r[1][3], tz = r[2][3];
#pragma unroll
    for (int i = 0; i < 3; ++i) {
        back[(size_t)k * 12 + i * 4 + 0] = (float)inv[i][0];
        back[(size_t)k * 12 + i * 4 + 1] = (float)inv[i][1];
        back[(size_t)k * 12 + i * 4 + 2] = (float)inv[i][2];
        back[(size_t)k * 12 + i * 4 + 3] = (float)(-(inv[i][0] * tx + inv[i][1] * ty + inv[i][2] * tz));
    }

    float bmn[3], bmx[3];
#pragma unroll
    for (int i = 0; i < 3; ++i) { bmn[i] = bbmin[k * 3 + i]; bmx[i] = bbmax[k * 3 + i]; }
#pragma unroll
    for (int c = 0; c < 8; ++c) {
        float cx = ((c >> 2) & 1) ? bmx[0] : bmn[0];
        float cy = ((c >> 1) & 1) ? bmx[1] : bmn[1];
        float cz = (c & 1) ? bmx[2] : bmn[2];
#pragma unroll
        for (int i = 0; i < 3; ++i) {
            float p = r[i][0] * cx + r[i][1] * cy + r[i][2] * cz + r[i][3];
            hp[(size_t)k * 24 + c * 3 + i] = p;
            out_hposed[(size_t)k * 24 + c * 3 + i] = p;
        }
    }
}

__global__ void k_fill(float4* __restrict__ p, int n4) {
    int i = blockIdx.x * blockDim.x + threadIdx.x;
    if (i < n4) p[i] = make_float4(-1.f, -1.f, -1.f, -1.f);
}

__global__ void k_inside(const float* __restrict__ back, const float* __restrict__ hp,
                         const float* __restrict__ bbmin, const float* __restrict__ bbmax,
                         const uint8_t* __restrict__ disB, const int* __restrict__ flag,
                         uint64_t* __restrict__ bm, uint32_t* __restrict__ rowCount) {
    int k = blockIdx.x;
    __shared__ float bk[12], hk[24], bmnk[3], bmxk[3];
    __shared__ uint32_t cntS;
    int t = threadIdx.x;
    if (t < 12) bk[t] = back[(size_t)k * 12 + t];
    if (t < 24) hk[t] = hp[(size_t)k * 24 + t];
    if (t < 3) { bmnk[t] = bbmin[k * 3 + t] + EPSF; bmxk[t] = bbmax[k * 3 + t] - EPSF; }
    if (t == 0) cntS = 0;
    __syncthreads();
    const bool isBool = (*flag) != 0;
    int wave = t >> 6, lane = t & 63;
    uint32_t myCount = 0;
#pragma unroll
    for (int q = 0; q < 4; ++q) {
        int widx = q * 4 + wave;
        bool bit = false;
        if (widx * 64 <= k) {  // wave-uniform: some column in this word is <= k
            int l = widx * 64 + lane;
            if (l <= k) {
                const float* bl = back + (size_t)l * 12;
                const float* hl = hp + (size_t)l * 24;
                float bmnl[3], bmxl[3];
#pragma unroll
                for (int i = 0; i < 3; ++i) {
                    bmnl[i] = bbmin[l * 3 + i] + EPSF;
                    bmxl[i] = bbmax[l * 3 + i] - EPSF;
                }
                bool rawA = false, rawB = false;
#pragma unroll
                for (int c = 0; c < 8; ++c) {  // corners of l into frame k
                    float px = hl[c * 3 + 0], py = hl[c * 3 + 1], pz = hl[c * 3 + 2];
                    float x = bk[0] * px + bk[1] * py + bk[2] * pz + bk[3];
                    float y = bk[4] * px + bk[5] * py + bk[6] * pz + bk[7];
                    float z = bk[8] * px + bk[9] * py + bk[10] * pz + bk[11];
                    rawA = rawA || (x > bmnk[0] && x < bmxk[0] && y > bmnk[1] && y < bmxk[1] &&
                                    z > bmnk[2] && z < bmxk[2]);
                }
#pragma unroll
                for (int c = 0; c < 8; ++c) {  // corners of k into frame l
                    float px = hk[c * 3 + 0], py = hk[c * 3 + 1], pz = hk[c * 3 + 2];
                    float x = bl[0] * px + bl[1] * py + bl[2] * pz + bl[3];
                    float y = bl[4] * px + bl[5] * py + bl[6] * pz + bl[7];
                    float z = bl[8] * px + bl[9] * py + bl[10] * pz + bl[11];
                    rawB = rawB || (x > bmnl[0] && x < bmxl[0] && y > bmnl[1] && y < bmxl[1] &&
                                    z > bmnl[2] && z < bmxl[2]);
                }
                bool dA, dB;
                if (isBool) {
                    dA = disB[(size_t)k * KBOX + l] != 0;
                    dB = disB[(size_t)l * KBOX + k] != 0;
                } else {
                    const int* disI = (const int*)disB;
                    dA = disI[(size_t)k * KBOX + l] != 0;
                    dB = disI[(size_t)l * KBOX + k] != 0;
                }
                bit = (rawA && dA) || (rawB && dB);
            }
        }
        uint64_t word = __ballot(bit ? 1 : 0);
        if (lane == 0) {
            bm[(size_t)k * 16 + widx] = word;
            myCount += (uint32_t)__popcll(word);
        }
    }
    if (lane == 0) atomicAdd(&cntS, myCount);
    __syncthreads();
    if (t == 0) rowCount[k] = cntS;
}

__global__ void k_scan(const uint32_t* __restrict__ cnt, uint32_t* __restrict__ start) {
    __shared__ uint32_t s[KBOX];
    int i = threadIdx.x;
    uint32_t v = cnt[i];
    s[i] = v;
    __syncthreads();
    for (int off = 1; off < KBOX; off <<= 1) {
        uint32_t u = (i >= off) ? s[i - off] : 0u;
        __syncthreads();
        s[i] += u;
        __syncthreads();
    }
    start[i] = s[i] - v;
}

__global__ void k_compact(const uint64_t* __restrict__ bm, const uint32_t* __restrict__ start,
                          float* __restrict__ out) {
    int k = blockIdx.x;
    int lane = threadIdx.x;  // 64 threads
    uint64_t w = (lane < 16) ? bm[(size_t)k * 16 + lane] : 0ull;
    int c = (int)__popcll(w);
    int p = c;
#pragma unroll
    for (int off = 1; off < 64; off <<= 1) {
        int u = __shfl_up(p, off);
        if (lane >= off) p += u;
    }
    int excl = p - c;
    int ofs = (int)start[k] + excl;
    float fk = (float)k;
    while (w) {
        int b = __builtin_ctzll(w);
        int col = lane * 64 + b;
        out[2 * (size_t)ofs + 0] = (float)col;  // min = col (tril => col <= row)
        out[2 * (size_t)ofs + 1] = fk;          // max = row
        ++ofs;
        w &= w - 1;
    }
}

extern "C" void kernel_launch(void* const* d_in, const int* in_sizes, int n_in,
                              void* d_out, int out_size, void* d_ws, size_t ws_size,
                              hipStream_t stream) {
    const float* bbmin = (const float*)d_in[0];
    const float* bbmax = (const float*)d_in[1];
    const float* A = (const float*)d_in[2];
    const uint8_t* dis = (const uint8_t*)d_in[3];
    float* out = (float*)d_out;

    char* ws = (char*)d_ws;
    int* flag = (int*)ws;
    float* back = (float*)(ws + BACK_OFF);
    float* hp = (float*)(ws + HP_OFF);
    uint64_t* bm = (uint64_t*)(ws + BM_OFF);
    uint32_t* rowCount = (uint32_t*)(ws + RC_OFF);
    uint32_t* rowStart = (uint32_t*)(ws + RS_OFF);

    k_flag<<<1, 256, 0, stream>>>(dis, flag);
    k_pose<<<KBOX / 256, 256, 0, stream>>>(bbmin, bbmax, A, back, hp, out);
    // output-1 region: 2*K*K floats = 524288 float4
    k_fill<<<(2 * KBOX * KBOX / 4) / 256, 256, 0, stream>>>((float4*)(out + KBOX * 24),
                                                            2 * KBOX * KBOX / 4);
    k_inside<<<KBOX, 256, 0, stream>>>(back, hp, bbmin, bbmax, dis, flag, bm, rowCount);
    k_scan<<<1, KBOX, 0, stream>>>(rowCount, rowStart);
    k_compact<<<KBOX, 64, 0, stream>>>(bm, rowStart, out + KBOX * 24);
}

// Round 3
// 29.139 us; speedup vs baseline: 1.2962x; 1.2962x over previous
//
#include <hip/hip_runtime.h>
#include <stdint.h>

#define KBOX 1024
#define EPSF 1e-4f
#define SLACK 3e-5f
#define FILL_BLOCKS 2048  // 2048*256 float4 = 2*K*K floats

// ws layout (bytes):
//   0      : int flag  (1 = bool byte layout, 0 = int32 layout)
//   16     : back [K][12] f32   (48 KB)   rows of inverse affine (3x4)
//   49168  : hp   [K][24] f32   (96 KB)   posed corners xyz
//   147472 : bm   [K][16] u64   (128 KB)  inside bitmask per row
//   278544 : rowCount [K] u32  (4 KB)
//   282640 : wmn  [K][4] f32   (16 KB)  world AABB min (slack-expanded)
//   299024 : wmx  [K][4] f32   (16 KB)  world AABB max
//   315408 : bne  [K][4] f32   (16 KB)  bb_min + EPS
//   331792 : bxe  [K][4] f32   (16 KB)  bb_max - EPS
#define BACK_OFF 16
#define HP_OFF   49168
#define BM_OFF   147472
#define RC_OFF   278544
#define WMN_OFF  282640
#define WMX_OFF  299024
#define BNE_OFF  315408
#define BXE_OFF  331792

__global__ void k_prep(const float* __restrict__ bbmin, const float* __restrict__ bbmax,
                       const float* __restrict__ A, const uint8_t* __restrict__ dis,
                       int* __restrict__ flag,
                       float* __restrict__ back, float* __restrict__ hp,
                       float* __restrict__ out_hposed,
                       float* __restrict__ wmn, float* __restrict__ wmx,
                       float* __restrict__ bne, float* __restrict__ bxe,
                       float4* __restrict__ fillp) {
    int bid = blockIdx.x;
    int t = threadIdx.x;
    if (bid < FILL_BLOCKS) {
        fillp[bid * 256 + t] = make_float4(-1.f, -1.f, -1.f, -1.f);
        return;
    }
    if (bid < FILL_BLOCKS + 4) {
        int k = (bid - FILL_BLOCKS) * 256 + t;
        const float* a = A + (size_t)k * 16;
        float r[3][4];
#pragma unroll
        for (int i = 0; i < 3; ++i)
#pragma unroll
            for (int j = 0; j < 4; ++j) r[i][j] = a[i * 4 + j];

        // double-precision analytic inverse of the 3x3 block
        double m00 = r[0][0], m01 = r[0][1], m02 = r[0][2];
        double m10 = r[1][0], m11 = r[1][1], m12 = r[1][2];
        double m20 = r[2][0], m21 = r[2][1], m22 = r[2][2];
        double c00 = m11 * m22 - m12 * m21;
        double c01 = m12 * m20 - m10 * m22;
        double c02 = m10 * m21 - m11 * m20;
        double det = m00 * c00 + m01 * c01 + m02 * c02;
        double id = 1.0 / det;
        double inv[3][3];
        inv[0][0] = c00 * id;
        inv[0][1] = (m02 * m21 - m01 * m22) * id;
        inv[0][2] = (m01 * m12 - m02 * m11) * id;
        inv[1][0] = c01 * id;
        inv[1][1] = (m00 * m22 - m02 * m20) * id;
        inv[1][2] = (m02 * m10 - m00 * m12) * id;
        inv[2][0] = c02 * id;
        inv[2][1] = (m01 * m20 - m00 * m21) * id;
        inv[2][2] = (m00 * m11 - m01 * m10) * id;
        double tx = r[0][3], ty = r[1][3], tz = r[2][3];
#pragma unroll
        for (int i = 0; i < 3; ++i) {
            back[(size_t)k * 12 + i * 4 + 0] = (float)inv[i][0];
            back[(size_t)k * 12 + i * 4 + 1] = (float)inv[i][1];
            back[(size_t)k * 12 + i * 4 + 2] = (float)inv[i][2];
            back[(size_t)k * 12 + i * 4 + 3] =
                (float)(-(inv[i][0] * tx + inv[i][1] * ty + inv[i][2] * tz));
        }

        float bmn[3], bmx[3];
#pragma unroll
        for (int i = 0; i < 3; ++i) { bmn[i] = bbmin[k * 3 + i]; bmx[i] = bbmax[k * 3 + i]; }
        *(float4*)(bne + (size_t)k * 4) =
            make_float4(bmn[0] + EPSF, bmn[1] + EPSF, bmn[2] + EPSF, 0.f);
        *(float4*)(bxe + (size_t)k * 4) =
            make_float4(bmx[0] - EPSF, bmx[1] - EPSF, bmx[2] - EPSF, 0.f);

        float wn[3] = {1e30f, 1e30f, 1e30f}, wx[3] = {-1e30f, -1e30f, -1e30f};
#pragma unroll
        for (int c = 0; c < 8; ++c) {
            float cx = ((c >> 2) & 1) ? bmx[0] : bmn[0];
            float cy = ((c >> 1) & 1) ? bmx[1] : bmn[1];
            float cz = (c & 1) ? bmx[2] : bmn[2];
#pragma unroll
            for (int i = 0; i < 3; ++i) {
                float p = r[i][0] * cx + r[i][1] * cy + r[i][2] * cz + r[i][3];
                hp[(size_t)k * 24 + c * 3 + i] = p;
                out_hposed[(size_t)k * 24 + c * 3 + i] = p;
                wn[i] = fminf(wn[i], p);
                wx[i] = fmaxf(wx[i], p);
            }
        }
        *(float4*)(wmn + (size_t)k * 4) =
            make_float4(wn[0] - SLACK, wn[1] - SLACK, wn[2] - SLACK, 0.f);
        *(float4*)(wmx + (size_t)k * 4) =
            make_float4(wx[0] + SLACK, wx[1] + SLACK, wx[2] + SLACK, 0.f);
        return;
    }
    // flag block: detect bool-byte vs int32 layout of selfpen_disable_mat
    __shared__ int s;
    if (t == 0) s = 0;
    __syncthreads();
    int acc = 0;
    for (int i = t; i < 4096; i += 256) {
        if ((i & 3) != 0 && dis[i] != 0) acc = 1;
    }
    if (acc) atomicOr(&s, 1);
    __syncthreads();
    if (t == 0) *flag = s;
}

__global__ void k_inside(const float* __restrict__ back, const float* __restrict__ hp,
                         const float* __restrict__ wmn, const float* __restrict__ wmx,
                         const float* __restrict__ bne, const float* __restrict__ bxe,
                         const uint8_t* __restrict__ disB, const int* __restrict__ flag,
                         uint64_t* __restrict__ bm, uint32_t* __restrict__ rowCount) {
    int k = blockIdx.x;
    __shared__ float bk[12], hk[24], bnek[3], bxek[3], wmnk[3], wmxk[3];
    __shared__ uint32_t cntS;
    int t = threadIdx.x;
    if (t < 12) bk[t] = back[(size_t)k * 12 + t];
    if (t < 24) hk[t] = hp[(size_t)k * 24 + t];
    if (t < 3) {
        bnek[t] = bne[(size_t)k * 4 + t];
        bxek[t] = bxe[(size_t)k * 4 + t];
        wmnk[t] = wmn[(size_t)k * 4 + t];
        wmxk[t] = wmx[(size_t)k * 4 + t];
    }
    if (t == 0) cntS = 0;
    __syncthreads();
    const bool isBool = (*flag) != 0;
    int wave = t >> 6, lane = t & 63;
    uint32_t myCount = 0;
#pragma unroll
    for (int q = 0; q < 4; ++q) {
        int widx = q * 4 + wave;
        if (widx * 64 > k) continue;  // wave-uniform; k_compact masks these words
        int l = widx * 64 + lane;
        bool dA = false, dB = false, cand = false;
        if (l <= k) {
            if (isBool) {
                dA = disB[(size_t)k * KBOX + l] != 0;
                dB = disB[(size_t)l * KBOX + k] != 0;
            } else {
                const int* disI = (const int*)disB;
                dA = disI[(size_t)k * KBOX + l] != 0;
                dB = disI[(size_t)l * KBOX + k] != 0;
            }
            if (dA | dB) {
                float4 ml = *(const float4*)(wmn + (size_t)l * 4);
                float4 xl = *(const float4*)(wmx + (size_t)l * 4);
                cand = (ml.x <= wmxk[0]) & (wmnk[0] <= xl.x) &
                       (ml.y <= wmxk[1]) & (wmnk[1] <= xl.y) &
                       (ml.z <= wmxk[2]) & (wmnk[2] <= xl.z);
            }
        }
        bool bit = false;
        if (__ballot(cand ? 1 : 0)) {  // wave-uniform skip of heavy geometry
            if (cand) {
                const float* hl = hp + (size_t)l * 24;
                const float* bl = back + (size_t)l * 12;
                if (dA) {
                    bool rawA = false;
#pragma unroll
                    for (int c = 0; c < 8; ++c) {  // corners of l into frame k
                        float px = hl[c * 3 + 0], py = hl[c * 3 + 1], pz = hl[c * 3 + 2];
                        float x = bk[0] * px + bk[1] * py + bk[2] * pz + bk[3];
                        float y = bk[4] * px + bk[5] * py + bk[6] * pz + bk[7];
                        float z = bk[8] * px + bk[9] * py + bk[10] * pz + bk[11];
                        rawA = rawA || (x > bnek[0] && x < bxek[0] && y > bnek[1] &&
                                        y < bxek[1] && z > bnek[2] && z < bxek[2]);
                    }
                    bit = rawA;
                }
                if (dB && !bit) {
                    float4 bnl = *(const float4*)(bne + (size_t)l * 4);
                    float4 bxl = *(const float4*)(bxe + (size_t)l * 4);
                    bool rawB = false;
#pragma unroll
                    for (int c = 0; c < 8; ++c) {  // corners of k into frame l
                        float px = hk[c * 3 + 0], py = hk[c * 3 + 1], pz = hk[c * 3 + 2];
                        float x = bl[0] * px + bl[1] * py + bl[2] * pz + bl[3];
                        float y = bl[4] * px + bl[5] * py + bl[6] * pz + bl[7];
                        float z = bl[8] * px + bl[9] * py + bl[10] * pz + bl[11];
                        rawB = rawB || (x > bnl.x && x < bxl.x && y > bnl.y &&
                                        y < bxl.y && z > bnl.z && z < bxl.z);
                    }
                    bit = rawB;
                }
            }
        }
        uint64_t word = __ballot(bit ? 1 : 0);
        if (lane == 0) {
            bm[(size_t)k * 16 + widx] = word;
            myCount += (uint32_t)__popcll(word);
        }
    }
    if (lane == 0 && myCount) atomicAdd(&cntS, myCount);
    __syncthreads();
    if (t == 0) rowCount[k] = cntS;
}

__global__ void k_compact(const uint64_t* __restrict__ bm,
                          const uint32_t* __restrict__ rowCount, float* __restrict__ out) {
    int k = blockIdx.x;
    int lane = threadIdx.x;  // 64 threads
    // start = sum_{r<k} rowCount[r], coalesced + wave reduce
    uint32_t s = 0;
    for (int r = lane; r < k; r += 64) s += rowCount[r];
#pragma unroll
    for (int off = 32; off > 0; off >>= 1) s += __shfl_down(s, off);
    uint32_t start = __shfl(s, 0);

    // FIX (round 2 bug): only words with lane*64 <= k are ever written by
    // k_inside; words beyond that hold stale ws garbage — mask them out.
    uint64_t w = (lane < 16 && lane * 64 <= k) ? bm[(size_t)k * 16 + lane] : 0ull;
    int c = (int)__popcll(w);
    int p = c;
#pragma unroll
    for (int off = 1; off < 64; off <<= 1) {
        int u = __shfl_up(p, off);
        if (lane >= off) p += u;
    }
    int ofs = (int)start + (p - c);
    float fk = (float)k;
    while (w) {
        int b = __builtin_ctzll(w);
        int col = lane * 64 + b;
        out[2 * (size_t)ofs + 0] = (float)col;  // min = col (tril => col <= row)
        out[2 * (size_t)ofs + 1] = fk;          // max = row
        ++ofs;
        w &= w - 1;
    }
}

extern "C" void kernel_launch(void* const* d_in, const int* in_sizes, int n_in,
                              void* d_out, int out_size, void* d_ws, size_t ws_size,
                              hipStream_t stream) {
    const float* bbmin = (const float*)d_in[0];
    const float* bbmax = (const float*)d_in[1];
    const float* A = (const float*)d_in[2];
    const uint8_t* dis = (const uint8_t*)d_in[3];
    float* out = (float*)d_out;

    char* ws = (char*)d_ws;
    int* flag = (int*)ws;
    float* back = (float*)(ws + BACK_OFF);
    float* hp = (float*)(ws + HP_OFF);
    uint64_t* bm = (uint64_t*)(ws + BM_OFF);
    uint32_t* rowCount = (uint32_t*)(ws + RC_OFF);
    float* wmn = (float*)(ws + WMN_OFF);
    float* wmx = (float*)(ws + WMX_OFF);
    float* bne = (float*)(ws + BNE_OFF);
    float* bxe = (float*)(ws + BXE_OFF);

    k_prep<<<FILL_BLOCKS + 5, 256, 0, stream>>>(bbmin, bbmax, A, dis, flag, back, hp, out,
                                                wmn, wmx, bne, bxe,
                                                (float4*)(out + KBOX * 24));
    k_inside<<<KBOX, 256, 0, stream>>>(back, hp, wmn, wmx, bne, bxe, dis, flag, bm, rowCount);
    k_compact<<<KBOX, 64, 0, stream>>>(bm, rowCount, out + KBOX * 24);
}